// Round 5
// baseline (259.630 us; speedup 1.0000x reference)
//
#include <hip/hip_runtime.h>

// GCN_77584289234976 — round 12.
// R11 post-mortem: FETCH fixed (41MB compulsory) but dur stuck at ~99us with
// ALL pipes idle (HBM 10%, Mfma 5%, VALU 8%, Occ 38%). R8-R11 ladder shows
// time is insensitive to traffic/occupancy/mapping -> the per-kt
// __syncthreads() is the serializer: its semantics drain vmcnt(0) every 24
// MFMAs, so no load survives a barrier (m218 counted-vs-drain0 lesson).
// R12: k_genapply v3 — 2-wave blocks (128 thr), 16n x 16o; wave w gens o-half
// into shared dbuf W, applies its b-half (full 16-wide MFMA N). Per-kt sync =
// raw s_barrier + lgkmcnt(0) ONLY: LDS sealed, global loads (pool kt+1, xg)
// fly across barriers with compiler counted vmcnt. Grid 1024 (4 blk/CU,
// 8 waves/CU), R11 node-pinned XCD map kept.
// MFMA 16x16x32 bf16 layout contract (m89/m97/m120):
//   a-frag: A[m][k], m=lane&15, k=(lane>>4)*8+j
//   b-frag: B[k][n], n=lane&15, k=(lane>>4)*8+j
//   d:      D[m][n], n(col)=lane&15, m(row)=(lane>>4)*4+reg

typedef unsigned short u16;
typedef unsigned int u32;
typedef __attribute__((ext_vector_type(8))) short bf16x8;
typedef __attribute__((ext_vector_type(4))) short bf16x4;
typedef __attribute__((ext_vector_type(4))) float f32x4;
typedef const __attribute__((address_space(1))) u16* gas1;
typedef __attribute__((address_space(3))) u16* las3;

#define NN 2048
#define EE 64
#define CC 128
#define BB 32

__device__ __forceinline__ u16 f2bf(float f) {
  u32 u = __builtin_bit_cast(u32, f);
  u += 0x7fffu + ((u >> 16) & 1u);   // round-to-nearest-even
  return (u16)(u >> 16);
}

__device__ __forceinline__ f32x4 mfma16(bf16x8 a, bf16x8 b, f32x4 c) {
  return __builtin_amdgcn_mfma_f32_16x16x32_bf16(a, b, c, 0, 0, 0);
}

// ---------------- mega0: prep(512) + poolt(256) + xtrans(1024), block-ranged
__global__ __launch_bounds__(256) void k_mega0(
    const float* __restrict__ x, const float* __restrict__ ne,
    const float* __restrict__ te, const float* __restrict__ pool,
    const float* __restrict__ bias_pool, const float* __restrict__ lnw,
    const float* __restrict__ lnb,
    float* __restrict__ e, u16* __restrict__ e_bf, float* __restrict__ bias_out,
    u16* __restrict__ pool_r, u16* __restrict__ x_t, u16* __restrict__ xg_t) {
  __shared__ __align__(16) char smem[33280];
  int bid = blockIdx.x;
  int tid = threadIdx.x;
  if (bid < 512) {
    // ---- prep: 4 nodes/block, one wave per node
    float* sh = (float*)smem;             // [4][64]
    int nw = tid >> 6, d = tid & 63;
    int n = bid * 4 + nw;
    float v = ne[n * EE + d] + te[d];
    float s = v;
#pragma unroll
    for (int off = 32; off > 0; off >>= 1) s += __shfl_xor(s, off);
    float mean = s * (1.0f / 64.0f);
    float c = v - mean;
    float q = c * c;
#pragma unroll
    for (int off = 32; off > 0; off >>= 1) q += __shfl_xor(q, off);
    float inv = rsqrtf(q * (1.0f / 64.0f) + 1e-12f);
    float ev = c * inv * lnw[d] + lnb[d];
    e[n * EE + d] = ev;
    e_bf[n * EE + d] = f2bf(ev);
    sh[nw * 64 + d] = ev;
    __syncthreads();
#pragma unroll
    for (int oo = 0; oo < 2; ++oo) {
      int o = oo * 64 + d;
      float acc = 0.f;
#pragma unroll 8
      for (int dd = 0; dd < 64; ++dd) acc += sh[nw * 64 + dd] * bias_pool[dd * CC + o];
      bias_out[n * CC + o] = acc;
    }
  } else if (bid < 768) {
    // ---- poolt: pool [d][ki][o] fp32 -> pool_r [(o,ki)][d] bf16
    float* t = (float*)smem;              // [128][65]
    int ki = bid - 512;
    for (int it = 0; it < 32; ++it) {
      int idx = it * 256 + tid;
      int d = idx >> 7, o = idx & 127;
      t[o * 65 + d] = pool[d * 32768 + ki * 128 + o];
    }
    __syncthreads();
    for (int it = 0; it < 32; ++it) {
      int idx = it * 256 + tid;
      int o = idx >> 6, d = idx & 63;
      pool_r[((size_t)o * 256 + ki) * 64 + d] = f2bf(t[o * 65 + d]);
    }
  } else {
    // ---- xtrans: x -> x_t [b][c][m] bf16 and xg_t [m][b][0..128) bf16
    u16* t = (u16*)smem;                  // [128][68]
    int bx = bid - 768;
    int b = bx >> 5;
    int m0 = (bx & 31) * 64;
    for (int it = 0; it < 32; ++it) {
      int idx = it * 256 + tid;
      int m = idx >> 7, c = idx & 127;
      float v = x[((size_t)b * NN + m0 + m) * CC + c];
      t[c * 68 + m] = f2bf(v);
    }
    __syncthreads();
    for (int it = 0; it < 32; ++it) {
      int idx = it * 256 + tid;
      int c = idx >> 6, m = idx & 63;
      x_t[((size_t)b * CC + c) * NN + m0 + m] = t[c * 68 + m];
    }
    for (int it = 0; it < 16; ++it) {
      int idx = it * 256 + tid;
      int m = idx >> 6, c2 = idx & 63;
      float2 v = *(const float2*)&x[((size_t)b * NN + m0 + m) * CC + c2 * 2];
      u32 pk = (u32)f2bf(v.x) | ((u32)f2bf(v.y) << 16);
      *(u32*)&xg_t[(((size_t)(m0 + m)) * 32 + b) * 256 + c2 * 2] = pk;
    }
  }
}

// ---------------- k_Sexp: P = exp(e @ e^T) bf16 + atomic row sums.
// 64x64 tile (35KB LDS -> 4 blk/CU), 4x4 per thread, no max-sub (|S|<=64).
__global__ __launch_bounds__(256) void k_Sexp(const float* __restrict__ e,
                                              u16* __restrict__ P,
                                              float* __restrict__ rs) {
  __shared__ float er[64 * 68];
  __shared__ float ec[64 * 68];
  int n0 = (blockIdx.x >> 5) * 64, m0 = (blockIdx.x & 31) * 64;
  int tid = threadIdx.x;
  for (int it = 0; it < 16; ++it) {
    int idx = it * 256 + tid;
    int r = idx >> 6, d = idx & 63;
    er[r * 68 + d] = e[(n0 + r) * EE + d];
    ec[r * 68 + d] = e[(m0 + r) * EE + d];
  }
  __syncthreads();
  int tx = tid & 15, ty = tid >> 4;
  float acc[4][4] = {};
  for (int d4 = 0; d4 < 64; d4 += 4) {
    f32x4 av[4], bv[4];
#pragma unroll
    for (int i = 0; i < 4; ++i) av[i] = *(const f32x4*)&er[(ty + 16 * i) * 68 + d4];
#pragma unroll
    for (int j = 0; j < 4; ++j) bv[j] = *(const f32x4*)&ec[(tx + 16 * j) * 68 + d4];
#pragma unroll
    for (int i = 0; i < 4; ++i)
#pragma unroll
      for (int j = 0; j < 4; ++j) {
        acc[i][j] += av[i][0] * bv[j][0];
        acc[i][j] += av[i][1] * bv[j][1];
        acc[i][j] += av[i][2] * bv[j][2];
        acc[i][j] += av[i][3] * bv[j][3];
      }
  }
#pragma unroll
  for (int i = 0; i < 4; ++i) {
    float s = 0.f;
#pragma unroll
    for (int j = 0; j < 4; ++j) {
      float pv = __expf(acc[i][j]);
      P[(size_t)(n0 + ty + 16 * i) * NN + m0 + tx + 16 * j] = f2bf(pv);
      s += pv;
    }
#pragma unroll
    for (int off = 8; off > 0; off >>= 1) s += __shfl_xor(s, off);  // reduce over tx
    if (tx == 0) atomicAdd(&rs[n0 + ty + 16 * i], s);
  }
}

// ---------------- k_aggr: x_agg[b] = (P @ x[b]) / l -> xg_t upper half.
// bid = mb*32 + b -> bid%8 = b%8: XCD pinned to 4 batches (2MB x_t
// L2-resident); P panels from L3/HBM once. Staging source XOR-swizzled
// (ch ^= row&7) so fragment ds_read_b128 spread 8 bank-groups (was 4).
__global__ __launch_bounds__(256, 4) void k_aggr(
    const u16* __restrict__ P, const u16* __restrict__ x_t,
    const float* __restrict__ rs, u16* __restrict__ xg_t) {
  __shared__ __align__(16) char smem[32768];
  int tid = threadIdx.x;
  int lane = tid & 63, w = tid >> 6;
  int lm = lane & 15, lq = lane >> 4;
  u16* As = (u16*)smem;               // [128][64] linear dest (global_load_lds)
  u16* Bs = (u16*)(smem + 16384);
  int b = blockIdx.x & 31, mb = blockIdx.x >> 5;
  int n0 = mb * 128;
  int wm = w >> 1, wn = w & 1;
  f32x4 acc[4][4] = {};
  const u16* a_src = P + (size_t)n0 * NN;
  const u16* b_src = x_t + (size_t)b * CC * NN;
  for (int kc = 0; kc < NN; kc += 64) {
    __syncthreads();
#pragma unroll
    for (int ii = 0; ii < 4; ++ii) {
      int idx = ii * 256 + tid;
      int row = idx >> 3, ch = idx & 7;
      int sc = kc + ((ch ^ (row & 7)) << 3);   // pre-swizzled source col
      __builtin_amdgcn_global_load_lds((gas1)(a_src + (size_t)row * NN + sc),
                                       (las3)(As + (size_t)(ii * 256 + w * 64) * 8), 16, 0, 0);
      __builtin_amdgcn_global_load_lds((gas1)(b_src + (size_t)row * NN + sc),
                                       (las3)(Bs + (size_t)(ii * 256 + w * 64) * 8), 16, 0, 0);
    }
    __syncthreads();
#pragma unroll
    for (int kk = 0; kk < 64; kk += 32) {
      int cb = (kk >> 3) + lq;                 // 16B chunk index (unswizzled)
      bf16x8 af[4], bq[4];
#pragma unroll
      for (int i = 0; i < 4; ++i) {
        int row = wm * 64 + i * 16 + lm;
        af[i] = *(const bf16x8*)&As[row * 64 + ((cb ^ (row & 7)) << 3)];
      }
#pragma unroll
      for (int j = 0; j < 4; ++j) {
        int row = wn * 64 + j * 16 + lm;
        bq[j] = *(const bf16x8*)&Bs[row * 64 + ((cb ^ (row & 7)) << 3)];
      }
#pragma unroll
      for (int i = 0; i < 4; ++i)
#pragma unroll
        for (int j = 0; j < 4; ++j)
          acc[i][j] = mfma16(af[i], bq[j], acc[i][j]);
    }
  }
#pragma unroll
  for (int i = 0; i < 4; ++i) {
    int nr = n0 + wm * 64 + i * 16 + lq * 4;
#pragma unroll
    for (int r = 0; r < 4; ++r) {
      float sc = 1.0f / rs[nr + r];
#pragma unroll
      for (int j = 0; j < 4; ++j) {
        int c = wn * 64 + j * 16 + lm;
        xg_t[((size_t)(nr + r) * 32 + b) * 256 + 128 + c] = f2bf(acc[i][j][r] * sc);
      }
    }
  }
}

// ---------------- k_genapply v3: fused W-gen + apply, barrier-light.
// Block = 128 thr (2 waves), tile = 16 nodes x 16 o, all 32 b.
//   wave w: GEN o-half [w*8, w*8+8) for all 16 nodes -> shared W dbuf;
//           APPLY all 16 o x 16 nodes for b-half [w*16, w*16+16).
// Per-kt sync: s_waitcnt lgkmcnt(0) + RAW s_barrier — global loads stay in
// flight across barriers (compiler counted vmcnt), only LDS is sealed.
// Mapping (R11): x=bid&7 owns nodes [x*256,+256); k=bid>>3: og=k&7,
// ng=x*16+(k>>3). Per-XCD per-kt window ~1MB L2-resident.
// Grid 1024 = 4 blk/CU = 8 waves/CU; LDS 37376B x4 = 149.5KB.
// LDS W buf: [16 nodes][16 o][32 ki], o-stride 36, node-stride 584.
#define GA_OS 36
#define GA_NS 584
__global__ __launch_bounds__(128, 2) void k_genapply(
    const u16* __restrict__ e_bf, const u16* __restrict__ pool_r,
    const u16* __restrict__ xg_t, const float* __restrict__ biasb,
    float* __restrict__ out) {
  __shared__ u16 W[2][16 * GA_NS];   // 2 x 18688 B = 37376 B
  int tid = threadIdx.x;
  int lane = tid & 63, w = tid >> 6;       // w = o-half (gen) / b-half (apply)
  int lm = lane & 15, lq = lane >> 4;
  int x = blockIdx.x & 7, k = blockIdx.x >> 3;     // x = XCD slot
  int og = k & 7, ng = x * 16 + (k >> 3);          // node-slice pinned to XCD
  int n0 = ng * 16, o0 = og * 16;

  // e b-frags: B[k=d][n=node], node = n0 + lm, d = ks*32 + lq*8 + j
  bf16x8 eB[2];
#pragma unroll
  for (int ks = 0; ks < 2; ++ks)
    eB[ks] = *(const bf16x8*)&e_bf[(n0 + lm) * EE + ks * 32 + lq * 8];

  // gen(kt): this wave's o-half of W[16n][16o][32ki] for ki tile kt*32..+31.
  // D: node = lm (col), ki_local = kc*16 + lq*4 + r (row).
  auto GEN = [&](int kt, u16* Wb) {
    int ki0 = kt * 32;
#pragma unroll
    for (int ot = 0; ot < 8; ++ot) {
      int o_l = w * 8 + ot;
      const u16* pb = pool_r + ((size_t)(o0 + o_l) * 256 + ki0 + lm) * 64 + lq * 8;
#pragma unroll
      for (int kc = 0; kc < 2; ++kc) {
        const u16* ap = pb + kc * 16 * 64;
        bf16x8 a0 = *(const bf16x8*)ap;          // d = lq*8..
        bf16x8 a1 = *(const bf16x8*)(ap + 32);   // d = 32+lq*8..
        f32x4 d = {0.f, 0.f, 0.f, 0.f};
        d = mfma16(a0, eB[0], d);
        d = mfma16(a1, eB[1], d);
        ushort4 h;
        h.x = f2bf(d[0]); h.y = f2bf(d[1]); h.z = f2bf(d[2]); h.w = f2bf(d[3]);
        *(ushort4*)&Wb[lm * GA_NS + o_l * GA_OS + kc * 16 + lq * 4] = h;
      }
    }
  };

  f32x4 acc[16] = {};
  // apply b-frag base: B[k=ki][n=b], b = w*16 + lm
  const u16* xbase = xg_t + (size_t)n0 * 32 * 256 + (w * 16 + lm) * 256 + lq * 8;

  auto APPLY = [&](int kt, const u16* Wb) {
    int ki0 = kt * 32;
#pragma unroll
    for (int i = 0; i < 16; ++i) {
      const u16* wp = &Wb[i * GA_NS + lm * GA_OS + lq * 8];
      bf16x4 wlo = *(const bf16x4*)wp;
      bf16x4 whi = *(const bf16x4*)(wp + 4);
      bf16x8 wA = __builtin_shufflevector(wlo, whi, 0, 1, 2, 3, 4, 5, 6, 7);
      bf16x8 xv = *(const bf16x8*)(xbase + (size_t)i * 32 * 256 + ki0);
      acc[i] = mfma16(wA, xv, acc[i]);
    }
  };

  GEN(0, &W[0][0]);
  asm volatile("s_waitcnt lgkmcnt(0)" ::: "memory");
  __builtin_amdgcn_s_barrier();
#pragma unroll
  for (int kt = 0; kt < 8; ++kt) {
    if (kt < 7) GEN(kt + 1, &W[(kt + 1) & 1][0]);
    APPLY(kt, &W[kt & 1][0]);
    asm volatile("s_waitcnt lgkmcnt(0)" ::: "memory");
    __builtin_amdgcn_s_barrier();
  }

  // ---- epilogue: D[m=o][n=b]: b = w*16+lm, o = o0 + lq*4 + r
  int b = w * 16 + lm;
#pragma unroll
  for (int i = 0; i < 16; ++i) {
    int n = n0 + i;
    float4 bv = *(const float4*)&biasb[n * CC + o0 + lq * 4];
    float4 o4;
    o4.x = acc[i][0] + bv.x;
    o4.y = acc[i][1] + bv.y;
    o4.z = acc[i][2] + bv.z;
    o4.w = acc[i][3] + bv.w;
    *(float4*)&out[((size_t)b * NN + n) * CC + o0 + lq * 4] = o4;
  }
}

extern "C" void kernel_launch(void* const* d_in, const int* in_sizes, int n_in,
                              void* d_out, int out_size, void* d_ws, size_t ws_size,
                              hipStream_t stream) {
  const float* x        = (const float*)d_in[0];
  const float* node_emb = (const float*)d_in[1];
  const float* time_emb = (const float*)d_in[2];
  const float* pool     = (const float*)d_in[3];
  const float* bias_pl  = (const float*)d_in[4];
  const float* ln_w     = (const float*)d_in[5];
  const float* ln_b     = (const float*)d_in[6];
  float* out = (float*)d_out;

  char* p = (char*)d_ws;
  auto alloc = [&](size_t bytes) {
    char* r = p;
    p += (bytes + 255) & ~(size_t)255;
    return r;
  };
  float* e      = (float*)alloc((size_t)NN * EE * 4);
  u16*   e_bf   = (u16*)  alloc((size_t)NN * EE * 2);
  float* biasb  = (float*)alloc((size_t)NN * CC * 4);
  u16*   Pm     = (u16*)  alloc((size_t)NN * NN * 2);          // exp(S), unnormalized
  float* rs     = (float*)alloc((size_t)NN * 4);               // row sums
  u16*   x_t    = (u16*)  alloc((size_t)BB * CC * NN * 2);
  u16*   xg_t   = (u16*)  alloc((size_t)NN * BB * 256 * 2);    // [node][batch][x||xagg]
  u16*   pool_r = (u16*)  alloc((size_t)128 * 256 * 64 * 2);

  if (ws_size < (size_t)(p - (char*)d_ws)) return;

  (void)hipMemsetAsync(rs, 0, (size_t)NN * 4, stream);

  k_mega0<<<1792, 256, 0, stream>>>(x, node_emb, time_emb, pool, bias_pl, ln_w, ln_b,
                                    e, e_bf, biasb, pool_r, x_t, xg_t);
  k_Sexp<<<1024, 256, 0, stream>>>(e, Pm, rs);
  k_aggr<<<512, 256, 0, stream>>>(Pm, x_t, rs, xg_t);
  k_genapply<<<1024, 128, 0, stream>>>(e_bf, pool_r, xg_t, biasb, out);
}

// Round 6
// 229.997 us; speedup vs baseline: 1.1288x; 1.1288x over previous
//
#include <hip/hip_runtime.h>

// GCN_77584289234976 — round 13.
// R8-R12 post-mortem: the fused genapply is structurally latency-bound —
// ~32 dependent per-lane scattered 16B loads per kt feed MFMAs directly;
// reg-dbuf needs >256 VGPR, LDS-staging needs >96KB -> pinned at ~100us
// across 5 structures. Revert to the materialized-W pipeline (R7, 238us
// best) and fix ITS weak link instead:
// (a) k_apply: W stored in MFMA-B-frag-friendly permuted layout
//     W_p[n][ks(8)][o(128)][ki%32] -> B-frag loads are fully-coalesced
//     1KB/wave b128 (was 16B scatter @512B stride, 2.4TB/s).
// (b) gen (in mega2) emits W_p via the same LDS transpose (64B-chunk
//     stores, full cachelines).
// (c) aggr (in mega2): R10 batch-pinned XCD map (bid%8=b%8 -> 2MB x_t
//     L2-resident) + XOR swizzle kills the 2x ds_read_b128 conflict.
// MFMA 16x16x32 bf16 layout contract (m89/m97/m120):
//   a-frag: A[m][k], m=lane&15, k=(lane>>4)*8+j
//   b-frag: B[k][n], n=lane&15, k=(lane>>4)*8+j
//   d:      D[m][n], n(col)=lane&15, m(row)=(lane>>4)*4+reg

typedef unsigned short u16;
typedef unsigned int u32;
typedef __attribute__((ext_vector_type(8))) short bf16x8;
typedef __attribute__((ext_vector_type(4))) float f32x4;
typedef const __attribute__((address_space(1))) u16* gas1;
typedef __attribute__((address_space(3))) u16* las3;

#define NN 2048
#define EE 64
#define CC 128
#define BB 32

__device__ __forceinline__ u16 f2bf(float f) {
  u32 u = __builtin_bit_cast(u32, f);
  u += 0x7fffu + ((u >> 16) & 1u);   // round-to-nearest-even
  return (u16)(u >> 16);
}

__device__ __forceinline__ f32x4 mfma16(bf16x8 a, bf16x8 b, f32x4 c) {
  return __builtin_amdgcn_mfma_f32_16x16x32_bf16(a, b, c, 0, 0, 0);
}

// ---------------- mega0: prep(512) + poolt(256) + xtrans(1024), block-ranged
__global__ __launch_bounds__(256) void k_mega0(
    const float* __restrict__ x, const float* __restrict__ ne,
    const float* __restrict__ te, const float* __restrict__ pool,
    const float* __restrict__ bias_pool, const float* __restrict__ lnw,
    const float* __restrict__ lnb,
    float* __restrict__ e, u16* __restrict__ e_bf, float* __restrict__ bias_out,
    u16* __restrict__ pool_r, u16* __restrict__ x_t, u16* __restrict__ xg_t) {
  __shared__ __align__(16) char smem[33280];
  int bid = blockIdx.x;
  int tid = threadIdx.x;
  if (bid < 512) {
    // ---- prep: 4 nodes/block, one wave per node
    float* sh = (float*)smem;             // [4][64]
    int nw = tid >> 6, d = tid & 63;
    int n = bid * 4 + nw;
    float v = ne[n * EE + d] + te[d];
    float s = v;
#pragma unroll
    for (int off = 32; off > 0; off >>= 1) s += __shfl_xor(s, off);
    float mean = s * (1.0f / 64.0f);
    float c = v - mean;
    float q = c * c;
#pragma unroll
    for (int off = 32; off > 0; off >>= 1) q += __shfl_xor(q, off);
    float inv = rsqrtf(q * (1.0f / 64.0f) + 1e-12f);
    float ev = c * inv * lnw[d] + lnb[d];
    e[n * EE + d] = ev;
    e_bf[n * EE + d] = f2bf(ev);
    sh[nw * 64 + d] = ev;
    __syncthreads();
#pragma unroll
    for (int oo = 0; oo < 2; ++oo) {
      int o = oo * 64 + d;
      float acc = 0.f;
#pragma unroll 8
      for (int dd = 0; dd < 64; ++dd) acc += sh[nw * 64 + dd] * bias_pool[dd * CC + o];
      bias_out[n * CC + o] = acc;
    }
  } else if (bid < 768) {
    // ---- poolt: pool [d][ki][o] fp32 -> pool_r [(o,ki)][d] bf16
    float* t = (float*)smem;              // [128][65]
    int ki = bid - 512;
    for (int it = 0; it < 32; ++it) {
      int idx = it * 256 + tid;
      int d = idx >> 7, o = idx & 127;
      t[o * 65 + d] = pool[d * 32768 + ki * 128 + o];
    }
    __syncthreads();
    for (int it = 0; it < 32; ++it) {
      int idx = it * 256 + tid;
      int o = idx >> 6, d = idx & 63;
      pool_r[((size_t)o * 256 + ki) * 64 + d] = f2bf(t[o * 65 + d]);
    }
  } else {
    // ---- xtrans: x -> x_t [b][c][m] bf16 and xg_t [m][b][0..128) bf16
    u16* t = (u16*)smem;                  // [128][68]
    int bx = bid - 768;
    int b = bx >> 5;
    int m0 = (bx & 31) * 64;
    for (int it = 0; it < 32; ++it) {
      int idx = it * 256 + tid;
      int m = idx >> 7, c = idx & 127;
      float v = x[((size_t)b * NN + m0 + m) * CC + c];
      t[c * 68 + m] = f2bf(v);
    }
    __syncthreads();
    for (int it = 0; it < 32; ++it) {
      int idx = it * 256 + tid;
      int c = idx >> 6, m = idx & 63;
      x_t[((size_t)b * CC + c) * NN + m0 + m] = t[c * 68 + m];
    }
    for (int it = 0; it < 16; ++it) {
      int idx = it * 256 + tid;
      int m = idx >> 6, c2 = idx & 63;
      float2 v = *(const float2*)&x[((size_t)b * NN + m0 + m) * CC + c2 * 2];
      u32 pk = (u32)f2bf(v.x) | ((u32)f2bf(v.y) << 16);
      *(u32*)&xg_t[(((size_t)(m0 + m)) * 32 + b) * 256 + c2 * 2] = pk;
    }
  }
}

// ---------------- k_Sexp: P = exp(e @ e^T) bf16 + atomic row sums.
// 64x64 tile (35KB LDS -> 4 blk/CU), 4x4 per thread, no max-sub (|S|<=64).
__global__ __launch_bounds__(256) void k_Sexp(const float* __restrict__ e,
                                              u16* __restrict__ P,
                                              float* __restrict__ rs) {
  __shared__ float er[64 * 68];
  __shared__ float ec[64 * 68];
  int n0 = (blockIdx.x >> 5) * 64, m0 = (blockIdx.x & 31) * 64;
  int tid = threadIdx.x;
  for (int it = 0; it < 16; ++it) {
    int idx = it * 256 + tid;
    int r = idx >> 6, d = idx & 63;
    er[r * 68 + d] = e[(n0 + r) * EE + d];
    ec[r * 68 + d] = e[(m0 + r) * EE + d];
  }
  __syncthreads();
  int tx = tid & 15, ty = tid >> 4;
  float acc[4][4] = {};
  for (int d4 = 0; d4 < 64; d4 += 4) {
    f32x4 av[4], bv[4];
#pragma unroll
    for (int i = 0; i < 4; ++i) av[i] = *(const f32x4*)&er[(ty + 16 * i) * 68 + d4];
#pragma unroll
    for (int j = 0; j < 4; ++j) bv[j] = *(const f32x4*)&ec[(tx + 16 * j) * 68 + d4];
#pragma unroll
    for (int i = 0; i < 4; ++i)
#pragma unroll
      for (int j = 0; j < 4; ++j) {
        acc[i][j] += av[i][0] * bv[j][0];
        acc[i][j] += av[i][1] * bv[j][1];
        acc[i][j] += av[i][2] * bv[j][2];
        acc[i][j] += av[i][3] * bv[j][3];
      }
  }
#pragma unroll
  for (int i = 0; i < 4; ++i) {
    float s = 0.f;
#pragma unroll
    for (int j = 0; j < 4; ++j) {
      float pv = __expf(acc[i][j]);
      P[(size_t)(n0 + ty + 16 * i) * NN + m0 + tx + 16 * j] = f2bf(pv);
      s += pv;
    }
#pragma unroll
    for (int off = 8; off > 0; off >>= 1) s += __shfl_xor(s, off);  // reduce over tx
    if (tx == 0) atomicAdd(&rs[n0 + ty + 16 * i], s);
  }
}

// ---------------- mega2: aggr(512 blocks, first) + gen(4096 blocks), block-ranged
// aggr: x_agg[b] = (P @ x[b]) / l -> xg_t upper half. R10 version: bid%8=b%8
// pins 4 batches' x_t (2MB) per XCD L2; XOR-swizzled staging+reads.
// gen: W_p[n][ks][o][ki%32] = e @ pool via LDS transpose, coalesced stores.
__global__ __launch_bounds__(256, 4) void k_mega2(
    const u16* __restrict__ P, const u16* __restrict__ x_t,
    const float* __restrict__ rs, u16* __restrict__ xg_t,
    const u16* __restrict__ e_bf, const u16* __restrict__ pool_r,
    u16* __restrict__ W_p) {
  __shared__ __align__(16) char smem[33792];
  int tid = threadIdx.x;
  int lane = tid & 63, w = tid >> 6;
  int lm = lane & 15, lq = lane >> 4;
  if (blockIdx.x < 512) {
    // ---- aggr
    u16* As = (u16*)smem;               // [128][64] linear dest (global_load_lds)
    u16* Bs = (u16*)(smem + 16384);
    int b = blockIdx.x & 31, mb = blockIdx.x >> 5;
    int n0 = mb * 128;
    int wm = w >> 1, wn = w & 1;
    f32x4 acc[4][4] = {};
    const u16* a_src = P + (size_t)n0 * NN;
    const u16* b_src = x_t + (size_t)b * CC * NN;
    for (int kc = 0; kc < NN; kc += 64) {
      __syncthreads();
#pragma unroll
      for (int ii = 0; ii < 4; ++ii) {
        int idx = ii * 256 + tid;
        int row = idx >> 3, ch = idx & 7;
        int sc = kc + ((ch ^ (row & 7)) << 3);   // pre-swizzled source col
        __builtin_amdgcn_global_load_lds((gas1)(a_src + (size_t)row * NN + sc),
                                         (las3)(As + (size_t)(ii * 256 + w * 64) * 8), 16, 0, 0);
        __builtin_amdgcn_global_load_lds((gas1)(b_src + (size_t)row * NN + sc),
                                         (las3)(Bs + (size_t)(ii * 256 + w * 64) * 8), 16, 0, 0);
      }
      __syncthreads();
#pragma unroll
      for (int kk = 0; kk < 64; kk += 32) {
        int cb = (kk >> 3) + lq;                 // 16B chunk index (unswizzled)
        bf16x8 af[4], bq[4];
#pragma unroll
        for (int i = 0; i < 4; ++i) {
          int row = wm * 64 + i * 16 + lm;
          af[i] = *(const bf16x8*)&As[row * 64 + ((cb ^ (row & 7)) << 3)];
        }
#pragma unroll
        for (int j = 0; j < 4; ++j) {
          int row = wn * 64 + j * 16 + lm;
          bq[j] = *(const bf16x8*)&Bs[row * 64 + ((cb ^ (row & 7)) << 3)];
        }
#pragma unroll
        for (int i = 0; i < 4; ++i)
#pragma unroll
          for (int j = 0; j < 4; ++j)
            acc[i][j] = mfma16(af[i], bq[j], acc[i][j]);
      }
    }
#pragma unroll
    for (int i = 0; i < 4; ++i) {
      int nr = n0 + wm * 64 + i * 16 + lq * 4;
#pragma unroll
      for (int r = 0; r < 4; ++r) {
        float sc = 1.0f / rs[nr + r];
#pragma unroll
        for (int j = 0; j < 4; ++j) {
          int c = wn * 64 + j * 16 + lm;
          xg_t[((size_t)(nr + r) * 32 + b) * 256 + 128 + c] = f2bf(acc[i][j][r] * sc);
        }
      }
    }
  } else {
    // ---- gen: one o (=cb) x 64 nodes per block; 256 ki via 16 ctiles.
    u16* Tl = (u16*)smem;               // [64][264]
    int bid = blockIdx.x - 512;
    int cb = bid & 127, nb = bid >> 7;  // o = cb; 32 node-blocks
    int c0 = cb * 256, n0 = nb * 64;
    bf16x8 eB[4][2];
#pragma unroll
    for (int nt = 0; nt < 4; ++nt)
#pragma unroll
      for (int ks = 0; ks < 2; ++ks)
        eB[nt][ks] = *(const bf16x8*)&e_bf[(n0 + nt * 16 + lm) * EE + ks * 32 + lq * 8];
#pragma unroll
    for (int ct = 0; ct < 4; ++ct) {
      int ctile = w * 4 + ct;
      const u16* ap = pool_r + ((size_t)c0 + ctile * 16 + lm) * 64 + lq * 8;
      bf16x8 pA0 = *(const bf16x8*)ap;
      bf16x8 pA1 = *(const bf16x8*)(ap + 32);
#pragma unroll
      for (int nt = 0; nt < 4; ++nt) {
        f32x4 g = {0.f, 0.f, 0.f, 0.f};
        g = mfma16(pA0, eB[nt][0], g);
        g = mfma16(pA1, eB[nt][1], g);
        ushort4 h;
        h.x = f2bf(g[0]); h.y = f2bf(g[1]); h.z = f2bf(g[2]); h.w = f2bf(g[3]);
        *(ushort4*)&Tl[(nt * 16 + lm) * 264 + ctile * 16 + lq * 4] = h;
      }
    }
    __syncthreads();
    // permuted store: W_p[n][ks][o][ki%32], elem addr =
    //   n*32768 + (ki/32)*4096 + o*32 + ki%32;  seg = ki/8.
#pragma unroll
    for (int it = 0; it < 8; ++it) {
      int idx = it * 256 + tid;
      int node = idx >> 5, seg = idx & 31;
      uint4 v = *(const uint4*)&Tl[node * 264 + seg * 8];
      *(uint4*)&W_p[(size_t)(n0 + node) * 32768 + (seg >> 2) * 4096 + cb * 32 + (seg & 3) * 8] = v;
    }
  }
}

// ---------------- k_apply v2: out[b,n,o] = xg[n] @ W[n] + bias.
// W_p permuted layout -> B-frag load = (ot*16+lm)*64B + lq*16B: 16 lanes x
// 64B fully-coalesced 1KB per wave instruction (was 16B @ 512B stride).
__global__ __launch_bounds__(256, 3) void k_apply(const u16* __restrict__ xg_t,
                                                  const u16* __restrict__ W_p,
                                                  const float* __restrict__ bias,
                                                  float* __restrict__ out) {
  int n0 = blockIdx.x * 2;
  int tid = threadIdx.x;
  int lane = tid & 63, w = tid >> 6;
  int lm = lane & 15, lq = lane >> 4;
  int n = n0 + (w & 1), oh = w >> 1;    // node, o-half(64)
  const u16* xb = xg_t + (size_t)n * 32 * 256;
  const u16* wb = W_p + (size_t)n * 32768 + (size_t)oh * 64 * 32;
  f32x4 acc[2][4] = {};
#pragma unroll
  for (int ks = 0; ks < 8; ++ks) {
    int ko = ks * 32 + lq * 8;
    bf16x8 a0 = *(const bf16x8*)&xb[lm * 256 + ko];
    bf16x8 a1 = *(const bf16x8*)&xb[(16 + lm) * 256 + ko];
#pragma unroll
    for (int ot = 0; ot < 4; ++ot) {
      bf16x8 bv = *(const bf16x8*)&wb[(size_t)ks * 4096 + (ot * 16 + lm) * 32 + lq * 8];
      acc[0][ot] = mfma16(a0, bv, acc[0][ot]);
      acc[1][ot] = mfma16(a1, bv, acc[1][ot]);
    }
  }
#pragma unroll
  for (int ot = 0; ot < 4; ++ot) {
    int oc = oh * 64 + ot * 16 + lm;
    float bv = bias[n * CC + oc];
#pragma unroll
    for (int mt = 0; mt < 2; ++mt)
#pragma unroll
      for (int r = 0; r < 4; ++r) {
        int b = mt * 16 + lq * 4 + r;
        out[((size_t)b * NN + n) * CC + oc] = acc[mt][ot][r] + bv;
      }
  }
}

extern "C" void kernel_launch(void* const* d_in, const int* in_sizes, int n_in,
                              void* d_out, int out_size, void* d_ws, size_t ws_size,
                              hipStream_t stream) {
  const float* x        = (const float*)d_in[0];
  const float* node_emb = (const float*)d_in[1];
  const float* time_emb = (const float*)d_in[2];
  const float* pool     = (const float*)d_in[3];
  const float* bias_pl  = (const float*)d_in[4];
  const float* ln_w     = (const float*)d_in[5];
  const float* ln_b     = (const float*)d_in[6];
  float* out = (float*)d_out;

  char* p = (char*)d_ws;
  auto alloc = [&](size_t bytes) {
    char* r = p;
    p += (bytes + 255) & ~(size_t)255;
    return r;
  };
  float* e      = (float*)alloc((size_t)NN * EE * 4);
  u16*   e_bf   = (u16*)  alloc((size_t)NN * EE * 2);
  float* biasb  = (float*)alloc((size_t)NN * CC * 4);
  u16*   Pm     = (u16*)  alloc((size_t)NN * NN * 2);          // exp(S), unnormalized
  float* rs     = (float*)alloc((size_t)NN * 4);               // row sums
  u16*   x_t    = (u16*)  alloc((size_t)BB * CC * NN * 2);
  u16*   xg_t   = (u16*)  alloc((size_t)NN * BB * 256 * 2);    // [node][batch][x||xagg]
  u16*   pool_r = (u16*)  alloc((size_t)128 * 256 * 64 * 2);
  u16*   W_p    = (u16*)  alloc((size_t)NN * 32768 * 2);       // 128 MB, permuted

  if (ws_size < (size_t)(p - (char*)d_ws)) return;

  (void)hipMemsetAsync(rs, 0, (size_t)NN * 4, stream);

  k_mega0<<<1792, 256, 0, stream>>>(x, node_emb, time_emb, pool, bias_pl, ln_w, ln_b,
                                    e, e_bf, biasb, pool_r, x_t, xg_t);
  k_Sexp<<<1024, 256, 0, stream>>>(e, Pm, rs);
  k_mega2<<<4608, 256, 0, stream>>>(Pm, x_t, rs, xg_t, e_bf, pool_r, W_p);
  k_apply<<<NN / 2, 256, 0, stream>>>(xg_t, W_p, biasb, out);
}